// Round 7
// baseline (277.055 us; speedup 1.0000x reference)
//
#include <hip/hip_runtime.h>

#define BB 4
#define HH 512
#define WW 512
#define KK 7
#define PP 3
#define CC 256
#define RS 32                     // region is RS x RS
#define SWD (RS + 2 * PP)         // 38
#define NT 512                    // threads per block (8 waves)
#define NWAVE (NT / 64)           // 8
#define NCHUNK 4
#define CHW (CC / NCHUNK)         // 64 floats per chunk
#define NREGION (BB * (HH / RS) * (WW / RS))   // 1024
#define NBLOCKS (NREGION * NCHUNK)             // 4096
#define MAXSITES (RS * RS)        // 1024

// Scatter active-site linear index into dense idx_map (pre-filled with -1).
__global__ void smconv_scatter(const int* __restrict__ idx,
                               int* __restrict__ idx_map, int n) {
    int i = blockIdx.x * blockDim.x + threadIdx.x;
    if (i >= n) return;
    int b = idx[i * 3 + 0];
    int y = idx[i * 3 + 1];
    int x = idx[i * 3 + 2];
    idx_map[((size_t)b * HH + y) * WW + x] = i;
}

// Transpose weight (C, K, K) -> (K*K, C) so channel-major loads coalesce.
__global__ void smconv_wt(const float* __restrict__ w, float* __restrict__ w_t) {
    int i = blockIdx.x * blockDim.x + threadIdx.x;
    if (i >= KK * KK * CC) return;
    int tap = i / CC;
    int c = i - tap * CC;
    w_t[i] = w[c * KK * KK + tap];
}

// One block = one 32x32 region x one 64-channel chunk. Rows are 256B so the
// per-XCD reuse window fits L2. Per-site tap masks built once (wave-per-site
// ballot); compute runs 4 sites per wave, 16 lanes x float4 per site.
__global__ void __launch_bounds__(NT, 8)
smconv_conv_cs(const float* __restrict__ feat,
               const float* __restrict__ w_t,
               const float* __restrict__ bias,
               const int* __restrict__ idx_map,
               float* __restrict__ out) {
    __shared__ int smap[SWD * SWD];                 //  5,776 B
    __shared__ unsigned short lst[MAXSITES];        //  2,048 B
    __shared__ unsigned long long msk[MAXSITES];    //  8,192 B
    __shared__ int srow[MAXSITES];                  //  4,096 B
    __shared__ int wcnt[NWAVE];
    __shared__ float w_lds[KK * KK * CHW];          // 12,544 B

    const int tid  = threadIdx.x;
    const int wave = tid >> 6;
    const int lane = tid & 63;

    // XCD-chunked swizzle: each XCD gets a contiguous slab of 512 work items
    // (scan-ordered regions within a chunk plane).
    const int Wk    = (blockIdx.x & 7) * (NBLOCKS / 8) + (blockIdx.x >> 3);
    const int chunk = Wk >> 10;               // 0..3
    const int R     = Wk & (NREGION - 1);     // 0..1023
    const int b  = R >> 8;
    const int rm = R & 255;
    const int rx = rm >> 4;                   // 16 column strips
    const int ry = rm & 15;                   // y-adjacent regions consecutive
    const int y0 = ry * RS;
    const int x0 = rx * RS;

    // Stage this chunk's weight columns: w_lds[t*CHW + c] = w_t[t*CC + chunk*CHW + c].
    for (int i = tid; i < KK * KK * CHW / 4; i += NT) {
        int t = i >> 4, c = i & 15;
        ((float4*)w_lds)[i] = ((const float4*)(w_t + t * CC + chunk * CHW))[c];
    }

    // Stage region+halo idx_map into LDS (-1 outside image).
    for (int i = tid; i < SWD * SWD; i += NT) {
        int gy = y0 + i / SWD - PP;
        int gx = x0 + i % SWD - PP;
        int v = -1;
        if (gy >= 0 && gy < HH && gx >= 0 && gx < WW)
            v = idx_map[((size_t)b * HH + gy) * WW + gx];
        smap[i] = v;
    }
    __syncthreads();

    // Build active-site list in deterministic scan order.
    int total = 0;
    for (int c0 = 0; c0 < RS * RS; c0 += NT) {
        int i = c0 + tid;
        int iy = i >> 5;
        int ix = i & (RS - 1);
        bool act = smap[(iy + PP) * SWD + (ix + PP)] >= 0;
        unsigned long long bal = __ballot(act);
        if (lane == 0) wcnt[wave] = __popcll(bal);
        __syncthreads();
        int off = total;
        for (int w = 0; w < wave; ++w) off += wcnt[w];
        if (act)
            lst[off + __popcll(bal & ((1ull << lane) - 1))] = (unsigned short)i;
        int t2 = total;
        for (int w = 0; w < NWAVE; ++w) t2 += wcnt[w];
        total = t2;
        __syncthreads();
    }

    // Per-site tap mask + output row id (wave per site, ballot over 49 taps).
    {
        const int dy = lane / KK;
        const int dx = lane % KK;
        for (int e = wave; e < total; e += NWAVE) {
            int pos = lst[e];
            int iy = pos >> 5;
            int ix = pos & (RS - 1);
            int nb = -1;
            if (lane < KK * KK)
                nb = smap[(iy + dy) * SWD + (ix + dx)];
            unsigned long long m = __ballot(nb >= 0);
            int sr = __builtin_amdgcn_readlane(nb, PP * KK + PP);
            if (lane == 0) { msk[e] = m; srow[e] = sr; }
        }
    }
    __syncthreads();

    // Compute: 4 sites per wave; group g = lanes [16g,16g+16), lane owns float4.
    const int g = lane >> 4;
    const int l = lane & 15;
    const float4 bv = ((const float4*)(bias + chunk * CHW))[l];
    const float4* feat4 = (const float4*)feat;
    const float4* wlds4 = (const float4*)w_lds;
    float4* out4 = (float4*)out;
    const int cho = chunk * (CHW / 4);   // float4 offset of chunk within a row

    for (int base = wave * 4; base < total; base += NWAVE * 4) {
        const int e = base + g;
        const bool have = e < total;
        unsigned long long m = have ? msk[e] : 0ull;
        const int pos = have ? lst[e] : 0;
        const int iy = pos >> 5;
        const int ix = pos & (RS - 1);
        const int sbase = iy * SWD + ix;   // site center sits at (iy+PP, ix+PP)

        float4 acc = make_float4(0.f, 0.f, 0.f, 0.f);

        while (__any(m != 0)) {
            bool a0 = m != 0;
            int t0 = a0 ? __ffsll((long long)m) - 1 : 0;
            if (a0) m &= m - 1;
            bool a1 = m != 0;
            int t1 = a1 ? __ffsll((long long)m) - 1 : 0;
            if (a1) m &= m - 1;

            if (a0) {
                int nb0 = smap[sbase + (t0 / KK) * SWD + (t0 % KK)];
                float4 f  = feat4[(size_t)nb0 * (CC / 4) + cho + l];
                float4 wv = wlds4[t0 * (CHW / 4) + l];
                acc.x = fmaf(f.x, wv.x, acc.x);
                acc.y = fmaf(f.y, wv.y, acc.y);
                acc.z = fmaf(f.z, wv.z, acc.z);
                acc.w = fmaf(f.w, wv.w, acc.w);
            }
            if (a1) {
                int nb1 = smap[sbase + (t1 / KK) * SWD + (t1 % KK)];
                float4 f  = feat4[(size_t)nb1 * (CC / 4) + cho + l];
                float4 wv = wlds4[t1 * (CHW / 4) + l];
                acc.x = fmaf(f.x, wv.x, acc.x);
                acc.y = fmaf(f.y, wv.y, acc.y);
                acc.z = fmaf(f.z, wv.z, acc.z);
                acc.w = fmaf(f.w, wv.w, acc.w);
            }
        }

        if (have) {
            float4 o = make_float4(acc.x + bv.x, acc.y + bv.y,
                                   acc.z + bv.z, acc.w + bv.w);
            out4[(size_t)srow[e] * (CC / 4) + cho + l] = o;
        }
    }
}

extern "C" void kernel_launch(void* const* d_in, const int* in_sizes, int n_in,
                              void* d_out, int out_size, void* d_ws, size_t ws_size,
                              hipStream_t stream) {
    const float* feat = (const float*)d_in[0];
    const int*   idx  = (const int*)d_in[1];
    const float* w    = (const float*)d_in[2];
    const float* bias = (const float*)d_in[3];
    float* out = (float*)d_out;

    const int n = in_sizes[0] / CC;  // number of active sites

    int*   idx_map = (int*)d_ws;
    float* w_t     = (float*)((char*)d_ws + (size_t)BB * HH * WW * sizeof(int));

    // 1) idx_map = -1
    hipMemsetAsync(idx_map, 0xFF, (size_t)BB * HH * WW * sizeof(int), stream);
    // 2) scatter site ids
    smconv_scatter<<<(n + 255) / 256, 256, 0, stream>>>(idx, idx_map, n);
    // 3) transpose weights to (tap, C)
    smconv_wt<<<(KK * KK * CC + 255) / 256, 256, 0, stream>>>(w, w_t);
    // 4) channel-split region conv: 1024 regions x 4 chunks, 4 blocks/CU
    smconv_conv_cs<<<NBLOCKS, NT, 0, stream>>>(feat, w_t, bias, idx_map, out);
}

// Round 8
// 269.773 us; speedup vs baseline: 1.0270x; 1.0270x over previous
//
#include <hip/hip_runtime.h>

#define BB 4
#define HH 512
#define WW 512
#define KK 7
#define PP 3
#define CC 256
#define RS 16                      // region is RS x RS
#define SD (RS + 2 * PP)           // 22 (region + halo)
#define NHALO (SD * SD)            // 484
#define NCORE (RS * RS)            // 256
#define NT 512                     // threads per block (8 waves)
#define NWAVE (NT / 64)            // 8
#define NCHUNK 2
#define CHF (CC / NCHUNK)          // 128 floats per chunk
#define CHF4 (CHF / 4)             // 32 float4 per chunk
#define ROWS 96                    // LDS row slots (avg active in halo = 92)
#define NREGION (BB * (HH / RS) * (WW / RS))   // 4096
#define NBLOCKS (NREGION * NCHUNK)             // 8192

// Scatter active-site linear index into dense idx_map (pre-filled with -1).
__global__ void smconv_scatter(const int* __restrict__ idx,
                               int* __restrict__ idx_map, int n) {
    int i = blockIdx.x * blockDim.x + threadIdx.x;
    if (i >= n) return;
    int b = idx[i * 3 + 0];
    int y = idx[i * 3 + 1];
    int x = idx[i * 3 + 2];
    idx_map[((size_t)b * HH + y) * WW + x] = i;
}

// Transpose weight (C, K, K) -> (K*K, C) so channel-major loads coalesce.
__global__ void smconv_wt(const float* __restrict__ w, float* __restrict__ w_t) {
    int i = blockIdx.x * blockDim.x + threadIdx.x;
    if (i >= KK * KK * CC) return;
    int tap = i / CC;
    int c = i - tap * CC;
    w_t[i] = w[c * KK * KK + tap];
}

#define FMA4(acc, f, wv)                          \
    acc.x = fmaf(f.x, wv.x, acc.x);               \
    acc.y = fmaf(f.y, wv.y, acc.y);               \
    acc.z = fmaf(f.z, wv.z, acc.z);               \
    acc.w = fmaf(f.w, wv.w, acc.w);

// Block = 16x16 region x 128-channel chunk. Active halo rows staged ONCE into
// LDS (512B slices); all gather reuse served from LDS, not the VMEM path.
// Compute: 2 sites per wave (32 lanes x float4), 4-deep tap peel.
__global__ void __launch_bounds__(NT, 4)
smconv_lds(const float* __restrict__ feat,
           const float* __restrict__ w_t,
           const float* __restrict__ bias,
           const int* __restrict__ idx_map,
           float* __restrict__ out) {
    __shared__ float rows[ROWS * CHF];              // 49,152 B
    __shared__ float w_lds[KK * KK * CHF];          // 25,088 B
    __shared__ int slotmap[NHALO];                  //  1,936 B
    __shared__ int gid[ROWS];                       //    384 B
    __shared__ unsigned short lst[NCORE];           //    512 B
    __shared__ unsigned long long msk[NCORE];       //  2,048 B
    __shared__ unsigned char offtab[64];            //     64 B
    __shared__ int wcnt[NWAVE];                     //     32 B

    const int tid  = threadIdx.x;
    const int wave = tid >> 6;
    const int lane = tid & 63;

    // XCD-chunked swizzle: XCD k owns 1024 consecutive work items.
    const int Wk    = (blockIdx.x & 7) * (NBLOCKS / 8) + (blockIdx.x >> 3);
    const int chunk = Wk >> 12;                // NREGION = 4096 = 2^12
    const int R     = Wk & (NREGION - 1);
    const int b  = R >> 10;                    // 1024 regions per batch
    const int rm = R & 1023;
    const int rx = rm >> 5;                    // 32 column strips
    const int ry = rm & 31;                    // y-adjacent regions consecutive
    const int y0 = ry * RS;
    const int x0 = rx * RS;

    // Phase 1: stage this chunk's weights; build tap-offset table.
    for (int i = tid; i < KK * KK * CHF4; i += NT) {
        int t = i >> 5, j = i & 31;            // CHF4 == 32
        ((float4*)w_lds)[i] = ((const float4*)w_t)[t * (CC / 4) + chunk * CHF4 + j];
    }
    if (tid < KK * KK)
        offtab[tid] = (unsigned char)((tid / KK) * SD + tid % KK);

    // Phase 2: slotmap over halo (slot id | -(gid+2) overflow | -1 inactive).
    int nhalo_act;
    {
        int g = -1;
        if (tid < NHALO) {
            int gy = y0 + tid / SD - PP;
            int gx = x0 + tid % SD - PP;
            if (gy >= 0 && gy < HH && gx >= 0 && gx < WW)
                g = idx_map[((size_t)b * HH + gy) * WW + gx];
        }
        bool act = g >= 0;
        unsigned long long bal = __ballot(act);
        if (lane == 0) wcnt[wave] = __popcll(bal);
        __syncthreads();
        int off = 0;
        for (int w = 0; w < wave; ++w) off += wcnt[w];
        int rank = off + __popcll(bal & ((1ull << lane) - 1));
        nhalo_act = 0;
        for (int w = 0; w < NWAVE; ++w) nhalo_act += wcnt[w];
        if (tid < NHALO) {
            if (act) {
                if (rank < ROWS) { slotmap[tid] = rank; gid[rank] = g; }
                else slotmap[tid] = -(g + 2);
            } else slotmap[tid] = -1;
        }
        __syncthreads();
    }
    const int nstage = nhalo_act < ROWS ? nhalo_act : ROWS;

    // Phase 3: active-site list over the 16x16 core (scan order).
    int total;
    {
        bool act = false;
        if (tid < NCORE) {
            int iy = tid >> 4, ix = tid & 15;
            act = slotmap[(iy + PP) * SD + (ix + PP)] != -1;
        }
        unsigned long long bal = __ballot(act);
        if (lane == 0) wcnt[wave] = __popcll(bal);
        __syncthreads();
        int off = 0;
        for (int w = 0; w < wave; ++w) off += wcnt[w];
        if (act)
            lst[off + __popcll(bal & ((1ull << lane) - 1))] = (unsigned short)tid;
        total = 0;
        for (int w = 0; w < NWAVE; ++w) total += wcnt[w];
        __syncthreads();
    }

    // Phase 4a: copy staged rows (512B chunk-slice each, coalesced).
    for (int s = tid >> 5; s < nstage; s += NT / 32) {
        int l = tid & 31;
        ((float4*)rows)[s * CHF4 + l] =
            ((const float4*)feat)[(size_t)gid[s] * (CC / 4) + chunk * CHF4 + l];
    }
    // Phase 4b: per-site tap masks (wave per site, ballot over 49 taps).
    for (int e = wave; e < total; e += NWAVE) {
        int pos = lst[e];
        int sb = (pos >> 4) * SD + (pos & 15);
        int v = -1;
        if (lane < KK * KK)
            v = slotmap[sb + offtab[lane]];
        unsigned long long m = __ballot(v != -1);
        if (lane == 0) msk[e] = m;
    }
    __syncthreads();

    // Phase 5: compute. 2 sites per wave; 32 lanes x float4 per site.
    const int g2 = lane >> 5;
    const int l  = lane & 31;
    const float4 bv = ((const float4*)bias)[chunk * CHF4 + l];
    const float4* feat4 = (const float4*)feat;
    const float4* rows4 = (const float4*)rows;
    const float4* w4    = (const float4*)w_lds;
    float4* out4 = (float4*)out;

    for (int base = wave * 2; base < total; base += NWAVE * 2) {
        const int e = base + g2;
        const bool have = e < total;
        unsigned long long m = have ? msk[e] : 0ull;
        const int pos = have ? lst[e] : 0;
        const int sb = (pos >> 4) * SD + (pos & 15);

        float4 acc = make_float4(0.f, 0.f, 0.f, 0.f);

        while (m) {
            int t0 = __ffsll((long long)m) - 1; m &= m - 1;
            bool a1 = m != 0;
            int t1 = a1 ? __ffsll((long long)m) - 1 : t0; if (a1) m &= m - 1;
            bool a2 = m != 0;
            int t2 = a2 ? __ffsll((long long)m) - 1 : t0; if (a2) m &= m - 1;
            bool a3 = m != 0;
            int t3 = a3 ? __ffsll((long long)m) - 1 : t0; if (a3) m &= m - 1;

            int v0 = slotmap[sb + offtab[t0]];
            int v1 = a1 ? slotmap[sb + offtab[t1]] : 0;
            int v2 = a2 ? slotmap[sb + offtab[t2]] : 0;
            int v3 = a3 ? slotmap[sb + offtab[t3]] : 0;

            {
                float4 f = (v0 >= 0) ? rows4[v0 * CHF4 + l]
                    : feat4[(size_t)(-(v0 + 2)) * (CC / 4) + chunk * CHF4 + l];
                float4 wv = w4[t0 * CHF4 + l];
                FMA4(acc, f, wv);
            }
            if (a1) {
                float4 f = (v1 >= 0) ? rows4[v1 * CHF4 + l]
                    : feat4[(size_t)(-(v1 + 2)) * (CC / 4) + chunk * CHF4 + l];
                float4 wv = w4[t1 * CHF4 + l];
                FMA4(acc, f, wv);
            }
            if (a2) {
                float4 f = (v2 >= 0) ? rows4[v2 * CHF4 + l]
                    : feat4[(size_t)(-(v2 + 2)) * (CC / 4) + chunk * CHF4 + l];
                float4 wv = w4[t2 * CHF4 + l];
                FMA4(acc, f, wv);
            }
            if (a3) {
                float4 f = (v3 >= 0) ? rows4[v3 * CHF4 + l]
                    : feat4[(size_t)(-(v3 + 2)) * (CC / 4) + chunk * CHF4 + l];
                float4 wv = w4[t3 * CHF4 + l];
                FMA4(acc, f, wv);
            }
        }

        if (have) {
            int vc = slotmap[sb + PP * SD + PP];       // center: always active
            int grow = vc >= 0 ? gid[vc] : -(vc + 2);
            float4 o = make_float4(acc.x + bv.x, acc.y + bv.y,
                                   acc.z + bv.z, acc.w + bv.w);
            out4[(size_t)grow * (CC / 4) + chunk * CHF4 + l] = o;
        }
    }
}

extern "C" void kernel_launch(void* const* d_in, const int* in_sizes, int n_in,
                              void* d_out, int out_size, void* d_ws, size_t ws_size,
                              hipStream_t stream) {
    const float* feat = (const float*)d_in[0];
    const int*   idx  = (const int*)d_in[1];
    const float* w    = (const float*)d_in[2];
    const float* bias = (const float*)d_in[3];
    float* out = (float*)d_out;

    const int n = in_sizes[0] / CC;  // number of active sites

    int*   idx_map = (int*)d_ws;
    float* w_t     = (float*)((char*)d_ws + (size_t)BB * HH * WW * sizeof(int));

    // 1) idx_map = -1
    hipMemsetAsync(idx_map, 0xFF, (size_t)BB * HH * WW * sizeof(int), stream);
    // 2) scatter site ids
    smconv_scatter<<<(n + 255) / 256, 256, 0, stream>>>(idx, idx_map, n);
    // 3) transpose weights to (tap, C)
    smconv_wt<<<(KK * KK * CC + 255) / 256, 256, 0, stream>>>(w, w_t);
    // 4) LDS-staged conv: 4096 regions x 2 chunks, 2 blocks/CU
    smconv_lds<<<NBLOCKS, NT, 0, stream>>>(feat, w_t, bias, idx_map, out);
}